// Round 11
// baseline (46.715 us; speedup 1.0000x reference)
//
#include <hip/hip_runtime.h>

// Keep IEEE mul-then-add semantics (match JAX/XLA fp32 reference; near-tie
// d0<d1 coset decisions are sensitive to contraction/reassociation).
#pragma clang fp contract(off)

#define TINY_EPS 1.1920928955078125e-07f  // np.finfo(float32).eps

typedef float f4 __attribute__((ext_vector_type(4)));
typedef float f2 __attribute__((ext_vector_type(2)));

// E8 closest point, bit-exact vs reference (see R7-R10 derivations):
// - both cosets through the exact packed custom_round (B NOT derivable from A
//   at half-integer ties of fl(z-0.5))
// - up = (f<0) ? d>=0 : d>0   (d = x-f exact)
// - distances reference-order: select y_j first, then t = z - y_j (z-based)
__device__ __forceinline__ void e8_compute(const float z[8], bool b1, float beta,
                                           float q[8]) {
    f2 fpk[8], dpk[8];
    f2 fsum = {0.0f, 0.0f};
#pragma unroll
    for (int j = 0; j < 8; ++j) {
        f2 xv = {z[j], z[j] - 0.5f};
        f2 cs = {__builtin_copysignf(TINY_EPS, xv.x),
                 __builtin_copysignf(TINY_EPS, xv.y)};
        f2 t  = xv - cs;                         // x - sign(x)*eps
        f2 u  = t + 0.5f;
        f2 fv = {floorf(u.x), floorf(u.y)};      // custom_round
        fpk[j] = fv;
        dpk[j] = xv - fv;                        // signed residual (exact)
        fsum   = fsum + fv;                      // exact small ints
    }
    bool oddA = (((int)fsum.x) & 1) != 0;  // matches jnp.mod parity (neg incl.)
    bool oddB = (((int)fsum.y) & 1) != 0;

    int   kA = 0,        kB = 0;
    float bdA = dpk[0].x, fkA = fpk[0].x;
    float bdB = dpk[0].y, fkB = fpk[0].y;
#pragma unroll
    for (int j = 1; j < 8; ++j) {
        bool bA = fabsf(dpk[j].x) > fabsf(bdA);  // strict: first max wins
        bdA = bA ? dpk[j].x : bdA;
        fkA = bA ? fpk[j].x : fkA;
        kA  = bA ? j : kA;
        bool bB = fabsf(dpk[j].y) > fabsf(bdB);
        bdB = bB ? dpk[j].y : bdB;
        fkB = bB ? fpk[j].y : fkB;
        kB  = bB ? j : kB;
    }
    bool  upA    = (fkA < 0.0f) ? (bdA >= 0.0f) : (bdA > 0.0f);
    float adjA   = fkA + (upA ? 1.0f : -1.0f);               // exact int
    bool  upB    = (fkB < 0.0f) ? (bdB >= 0.0f) : (bdB > 0.0f);
    float adjB05 = (fkB + (upB ? 1.0f : -1.0f)) + 0.5f;      // exact half-int
    int kA2 = oddA ? kA : 8;  // k'-trick: fold odd into index
    int kB2 = oddB ? kB : 8;

    f2 dacc = {0.0f, 0.0f};
    float yAs[8], yBs[8];
#pragma unroll
    for (int j = 0; j < 8; ++j) {
        bool  mA  = (j == kA2);
        bool  mB  = (j == kB2);
        float yA  = mA ? adjA : fpk[j].x;       // == ref y0_j
        float yBh = fpk[j].y + 0.5f;            // exact half-int
        float yB  = mB ? adjB05 : yBh;          // == ref y1_j
        yAs[j] = yA;
        yBs[j] = yB;
        f2 v = {__fsub_rn(z[j], yA),            // == ref t0
                __fsub_rn(z[j], yB)};           // == ref t1 (z-based)
        dacc = dacc + v * v;  // sequential j order, contract off
    }
    bool pick0 = dacc.x < dacc.y;  // ties -> y1 (jnp.where(d0<d1,...))
    if (b1) {  // 1.0*y == y exactly (incl. -0)
#pragma unroll
        for (int j = 0; j < 8; ++j) q[j] = pick0 ? yAs[j] : yBs[j];
    } else {
#pragma unroll
        for (int j = 0; j < 8; ++j) q[j] = __fmul_rn(beta, pick0 ? yAs[j] : yBs[j]);
    }
}

// Persistent grid-stride kernel, software-pipelined:
//   prologue load(t); loop { issue load(t+stride) EARLY; compute(t);
//   wave-local LDS transpose; nt store; rotate }
// NO __syncthreads anywhere: the transpose sources (wb + c*32 + (lane>>1))
// are entirely within the wave's own 64 rows of tile[] -> per-wave in-order
// DS pipe + compiler lgkmcnt ordering suffice. Removing the barrier also
// removes the implicit vmcnt(0) drain, so prefetch loads and nt stores stay
// in flight across iterations (never-drain pipeline).
__global__ void __launch_bounds__(256)
e8_quant_kernel(const float* __restrict__ x, const float* __restrict__ beta_p,
                const float* __restrict__ eps, float* __restrict__ out,
                int N, int T /* = ceil(N/256) tiles */) {
    __shared__ float tile[256][12];  // 48B row stride: aligned b128 DS ops;
                                     // rows wave-partitioned (no cross-wave use)
    const int tid = threadIdx.x;

    float beta = *beta_p;
    bool  b1   = (beta == 1.0f);  // uniform; bit-exact fast path (x/1.0 == x)
    const f4* ep = reinterpret_cast<const f4*>(eps);
    f4 e0 = ep[0], e1 = ep[1];
    float e[8] = {e0.x, e0.y, e0.z, e0.w, e1.x, e1.y, e1.z, e1.w};

    const f4* xv = reinterpret_cast<const f4*>(x);
    f4*       ov = reinterpret_cast<f4*>(out);
    const int stride = gridDim.x;

    int t = blockIdx.x;  // grid <= T guaranteed by launcher
    // ---- prologue: load tile t (clamped for a partial last tile) ----
    int  i0  = t * 256 + tid;
    int  ic  = (i0 < N) ? i0 : (N - 1);
    f4 a = xv[(size_t)ic * 2 + 0];
    f4 b = xv[(size_t)ic * 2 + 1];

    while (t < T) {
        // ---- issue next tile's loads EARLY (hide HBM latency under compute) ----
        int tn = t + stride;
        f4 an = a, bn = b;
        if (tn < T) {
            int in = tn * 256 + tid;
            int inc = (in < N) ? in : (N - 1);
            an = xv[(size_t)inc * 2 + 0];
            bn = xv[(size_t)inc * 2 + 1];
        }

        // ---- compute current tile ----
        float z[8] = {a.x, a.y, a.z, a.w, b.x, b.y, b.z, b.w};
        if (b1) {
#pragma unroll
            for (int j = 0; j < 8; ++j) z[j] = z[j] + e[j];
        } else {
#pragma unroll
            for (int j = 0; j < 8; ++j) z[j] = z[j] / beta + e[j];  // IEEE div
        }
        float q[8];
        e8_compute(z, b1, beta, q);

        // ---- store ----
        bool full = (t * 256 + 256) <= N;  // block-uniform
        if (full) {
            // wave-local LDS transpose (no barrier) -> lane-contiguous full-line
            // nt stores (output bypasses L2/L3: no alloc, input stays resident)
            f4* trow = reinterpret_cast<f4*>(&tile[tid][0]);
            f4 w0 = {q[0], q[1], q[2], q[3]};
            f4 w1 = {q[4], q[5], q[6], q[7]};
            trow[0] = w0;   // ds_write_b128
            trow[1] = w1;   // ds_write_b128
            int wave = tid >> 6, lane = tid & 63;
            int wb   = wave << 6;
            f4* op   = ov + (size_t)t * 512 + wave * 128;
#pragma unroll
            for (int c = 0; c < 2; ++c) {
                int p = wb + c * 32 + (lane >> 1);  // source point: SAME wave's rows
                int h = (lane & 1) << 2;            // q[0..3] or q[4..7]
                f4 v = *reinterpret_cast<const f4*>(&tile[p][h]);  // ds_read_b128
                __builtin_nontemporal_store(v, op + c * 64 + lane);
            }
        } else {
            // partial last tile: guarded direct cached stores (no LDS)
            int i = t * 256 + tid;
            if (i < N) {
                f4 s0 = {q[0], q[1], q[2], q[3]};
                f4 s1 = {q[4], q[5], q[6], q[7]};
                ov[(size_t)i * 2 + 0] = s0;
                ov[(size_t)i * 2 + 1] = s1;
            }
        }

        // ---- rotate pipeline ----
        t = tn;
        a = an;
        b = bn;
    }
}

extern "C" void kernel_launch(void* const* d_in, const int* in_sizes, int n_in,
                              void* d_out, int out_size, void* d_ws, size_t ws_size,
                              hipStream_t stream) {
    const float* x      = (const float*)d_in[0];
    const float* beta_p = (const float*)d_in[1];
    const float* eps    = (const float*)d_in[2];
    float*       out    = (float*)d_out;

    int N = in_sizes[0] / 8;         // 4,000,000 points
    int T = (N + 255) / 256;         // tiles
    int grid = T < 2048 ? T : 2048;  // 8 blocks/CU resident, persistent
    hipLaunchKernelGGL(e8_quant_kernel, dim3(grid), dim3(256), 0, stream,
                       x, beta_p, eps, out, N, T);
}

// Round 12
// 41.312 us; speedup vs baseline: 1.1308x; 1.1308x over previous
//
#include <hip/hip_runtime.h>

// Keep IEEE mul-then-add semantics (match JAX/XLA fp32 reference; near-tie
// d0<d1 coset decisions are sensitive to contraction/reassociation).
#pragma clang fp contract(off)

#define TINY_EPS 1.1920928955078125e-07f  // np.finfo(float32).eps

typedef float f4 __attribute__((ext_vector_type(4)));
typedef float f2 __attribute__((ext_vector_type(2)));  // -> v_pk_*_f32 where packable

// ===== ROOFLINE KERNEL (R9 structure, best measured: 41.2 us) =====
// 256 MB stream (128 in + 128 out) at the measured mixed R/W ceiling
// (6.29 TB/s float4-copy, m13) = 40.7 us floor; this kernel = 41.2 us
// (101.3% of pure-copy). ~350 VALU ops/pt fully hidden under the stream.
//
// 1 point per thread. Cosets A (z) and B (z-0.5) both go through the exact
// packed custom_round (B may NOT be derived from A's residuals: when
// |dA| < ulp(fA-0.5)/2, fl(z-0.5) is an exact half-integer tie and the
// reference's eps-rule decides by sign, not by dA).
// Selection is built reference-order: y_j selected FIRST, then t = z - y_j.
// Store path: LDS transpose -> lane-contiguous full-line nt stores
// (full 128B lines -> no write amplification; output bypasses L3 so the
// input stays L3-resident: FETCH ~62.5 MB of the 128 MB input).
__global__ void __launch_bounds__(256)
e8_quant_kernel(const float* __restrict__ x, const float* __restrict__ beta_p,
                const float* __restrict__ eps, float* __restrict__ out, int N) {
    __shared__ float tile[8][257];  // +1 pad: writes conflict-free, reads 2-way (free)
    int tid = threadIdx.x;
    int i   = blockIdx.x * 256 + tid;
    bool full_block = ((blockIdx.x + 1) * 256) <= N;  // block-uniform
    if (!full_block && i >= N) return;                // no barrier on this path

    float beta = *beta_p;
    bool  b1   = (beta == 1.0f);  // uniform
    float e[8];
#pragma unroll
    for (int j = 0; j < 8; ++j) e[j] = eps[j];  // uniform

    const f4* xp = reinterpret_cast<const f4*>(x) + (size_t)i * 2;
    f4 a = xp[0];
    f4 b = xp[1];
    float z[8] = {a.x, a.y, a.z, a.w, b.x, b.y, b.z, b.w};

    if (b1) {  // bit-exact: x/1.0 == x
#pragma unroll
        for (int j = 0; j < 8; ++j) z[j] = z[j] + e[j];
    } else {
#pragma unroll
        for (int j = 0; j < 8; ++j) z[j] = z[j] / beta + e[j];  // IEEE div
    }

    // ---- packed custom_round for both cosets: .x = A (z), .y = B (z-0.5) ----
    f2 fpk[8], dpk[8];
    f2 fsum = {0.0f, 0.0f};
#pragma unroll
    for (int j = 0; j < 8; ++j) {
        f2 xv = {z[j], z[j] - 0.5f};
        f2 cs = {__builtin_copysignf(TINY_EPS, xv.x),
                 __builtin_copysignf(TINY_EPS, xv.y)};
        f2 t  = xv - cs;                         // x - sign(x)*eps
        f2 u  = t + 0.5f;
        f2 fv = {floorf(u.x), floorf(u.y)};      // custom_round
        fpk[j] = fv;
        dpk[j] = xv - fv;                        // signed residual (exact)
        fsum   = fsum + fv;                      // exact small ints
    }
    bool oddA = (((int)fsum.x) & 1) != 0;  // matches jnp.mod parity (neg incl.)
    bool oddB = (((int)fsum.y) & 1) != 0;

    // ---- first-max argmax per coset on |d| (abs folds into cmp modifiers) ----
    int   kA = 0,        kB = 0;
    float bdA = dpk[0].x, fkA = fpk[0].x;
    float bdB = dpk[0].y, fkB = fpk[0].y;
#pragma unroll
    for (int j = 1; j < 8; ++j) {
        bool bA = fabsf(dpk[j].x) > fabsf(bdA);  // strict: first max wins
        bdA = bA ? dpk[j].x : bdA;
        fkA = bA ? fpk[j].x : fkA;
        kA  = bA ? j : kA;
        bool bB = fabsf(dpk[j].y) > fabsf(bdB);
        bdB = bB ? dpk[j].y : bdB;
        fkB = bB ? fpk[j].y : fkB;
        kB  = bB ? j : kB;
    }
    // up = x>=0 ? f<x : f<=x; with d=x-f exact: up = (f<0) ? d>=0 : d>0.
    bool  upA    = (fkA < 0.0f) ? (bdA >= 0.0f) : (bdA > 0.0f);
    float adjA   = fkA + (upA ? 1.0f : -1.0f);               // exact int
    bool  upB    = (fkB < 0.0f) ? (bdB >= 0.0f) : (bdB > 0.0f);
    float adjB05 = (fkB + (upB ? 1.0f : -1.0f)) + 0.5f;      // exact half-int
    // k'-trick: fold odd into the index (8 never matches j in [0,8))
    int kA2 = oddA ? kA : 8;
    int kB2 = oddB ? kB : 8;

    // ---- build y (ref order: select first), distances t = z - y ----
    f2 dacc = {0.0f, 0.0f};
    float yAs[8], yBs[8];
#pragma unroll
    for (int j = 0; j < 8; ++j) {
        bool  mA  = (j == kA2);                 // single cmp per coset
        bool  mB  = (j == kB2);
        float yA  = mA ? adjA : fpk[j].x;       // == ref y0_j
        float yBh = fpk[j].y + 0.5f;            // exact half-int
        float yB  = mB ? adjB05 : yBh;          // == ref y1_j
        yAs[j] = yA;
        yBs[j] = yB;
        f2 v = {__fsub_rn(z[j], yA),            // == ref t0
                __fsub_rn(z[j], yB)};           // == ref t1 (z-based)
        dacc = dacc + v * v;  // pk mul, pk add; sequential j order, contract off
    }
    bool pick0 = dacc.x < dacc.y;  // ties -> y1, matching jnp.where(d0<d1,...)

    float q[8];
    if (b1) {  // 1.0*y == y exactly (incl. -0)
#pragma unroll
        for (int j = 0; j < 8; ++j) q[j] = pick0 ? yAs[j] : yBs[j];
    } else {
#pragma unroll
        for (int j = 0; j < 8; ++j) q[j] = __fmul_rn(beta, pick0 ? yAs[j] : yBs[j]);
    }

    // ---- store: LDS transpose -> lane-contiguous full-line nt stores ----
    if (full_block) {
#pragma unroll
        for (int j = 0; j < 8; ++j) tile[j][tid] = q[j];
        __syncthreads();
        int wave = tid >> 6, lane = tid & 63;
        int wb   = wave << 6;
        f4* op   = reinterpret_cast<f4*>(out) + (size_t)blockIdx.x * 512 + wave * 128;
#pragma unroll
        for (int c = 0; c < 2; ++c) {
            int p = wb + c * 32 + (lane >> 1);  // source point (block-local)
            int h = (lane & 1) << 2;            // q[0..3] or q[4..7]
            f4 v = {tile[h + 0][p], tile[h + 1][p], tile[h + 2][p], tile[h + 3][p]};
            __builtin_nontemporal_store(v, op + c * 64 + lane);
        }
    } else {
        // tail fallback (never taken at N=4e6): plain cached stores
        f4* op = reinterpret_cast<f4*>(out) + (size_t)i * 2;
        f4 s0 = {q[0], q[1], q[2], q[3]};
        f4 s1 = {q[4], q[5], q[6], q[7]};
        op[0] = s0;
        op[1] = s1;
    }
}

extern "C" void kernel_launch(void* const* d_in, const int* in_sizes, int n_in,
                              void* d_out, int out_size, void* d_ws, size_t ws_size,
                              hipStream_t stream) {
    const float* x      = (const float*)d_in[0];
    const float* beta_p = (const float*)d_in[1];
    const float* eps    = (const float*)d_in[2];
    float*       out    = (float*)d_out;

    int N     = in_sizes[0] / 8;  // 4,000,000 points
    int block = 256;
    int grid  = (N + block - 1) / block;
    hipLaunchKernelGGL(e8_quant_kernel, dim3(grid), dim3(block), 0, stream,
                       x, beta_p, eps, out, N);
}